// Round 3
// baseline (176.758 us; speedup 1.0000x reference)
//
#include <hip/hip_runtime.h>
#include <string.h>

// Integer-quantized MHA. Phase 1: exact-int i8 K=64 MFMA digit GEMM, TRANSPOSED
// (C[s][t] via mfma(K,Q)) so the S-axis quant group is lane-local. Phase 2:
// native bf16 MFMA (r_q<=255, vt mantissa 8-bit -> exact products).
// R9 changes vs R8 (152us total, mha=61us, VALUBusy 40%, MfmaUtil 16%,
// LDS conflicts 5.77M):
//  - TT=32: each block computes 32 t-rows (scv[2][16][4], 2 Q-tile halves share
//    every kd/vd load). L2 traffic halves: 1GB -> 512MB (L2 was ~50% of wall).
//    1024 blocks, __launch_bounds__(256,2), rbuf 64KB -> 2 blocks/CU.
//  - swizzle FIXED: old one double-stepped (slot ~ 2*ln mod 8 -> quarters hit
//    only even slots, 4-8 way conflicts). New: RST=1024 (stride = 0 mod 128),
//    gs = (g & ~7) | ((g + (ln&7)) & 7): per 16-lane quarter each bank-group
//    position hit exactly 2x = hardware minimum for b128.
//  - ch loop force-unrolled so runtime st never sends scv to scratch.
// B=2,H=16 (BH=32), T=S=1024, HC=128, G=8. Output int32.

typedef int   v4i __attribute__((ext_vector_type(4)));
typedef float v4f __attribute__((ext_vector_type(4)));
typedef short v8s __attribute__((ext_vector_type(8)));
typedef unsigned v2u __attribute__((ext_vector_type(2)));

#define BHN 32
#define TN  1024
#define SN  1024
#define HCN 128
#define TT  32
#define KD_BH 262144           // 8 chunks * 32 KB (2 planes, fragment-ordered)
#define VD_BH 262144           // 32 kb * 8 n * 64 lanes * 16 B (bf16 frags)
#define WS_NEED ((size_t)BHN*(KD_BH+VD_BH))   // 16 MB

__device__ __forceinline__ unsigned pack_b(int b0,int b1,int b2,int b3){
    return (unsigned)((b0&255)|((b1&255)<<8)|((b2&255)<<16)|((b3&255)<<24));
}

// digitize 16 consecutive dequantized ints (2 scale groups) into hi/lo i8 digit vectors
__device__ __forceinline__ void dig16(const int* __restrict__ p, int s0, int s1,
                                      v4i& hi, v4i& lo){
    #pragma unroll
    for (int wi=0; wi<4; ++wi){
        v4i m = *(const v4i*)(p + wi*4);
        int s = (wi<2) ? s0 : s1;
        int d0=m[0]<<s, d1=m[1]<<s, d2=m[2]<<s, d3=m[3]<<s;
        hi[wi] = (int)pack_b(d0>>4,d1>>4,d2>>4,d3>>4);
        lo[wi] = (int)pack_b(d0&15,d1&15,d2&15,d3&15);
    }
}

__device__ __forceinline__ unsigned short bf16_of_int(int v){
    return (unsigned short)(__float_as_uint((float)v) >> 16);   // exact: <=8 sig bits
}

// ---------------- pre-pass (gather form: coalesced stores) ----------------
// kd: per bh, [ch(8)][n(8)][kc(2)][plane(2:hi,lo)][lane64][16B]
// vd: per bh, [kb(32)][n(8)][lane64][16B]  (8 bf16 per lane)
// One wave per fragment tile: wave stores lane*16 -> contiguous 1KB per store.
// Tasks: 0..4095 = kd (bh*128+ch*16+n*2+kc); 4096..12287 = vd (bh*256+kb*8+n).
__global__ __launch_bounds__(256) void digitize(
    const int* __restrict__ k_q, const int* __restrict__ k_s,
    const int* __restrict__ vt_q, const int* __restrict__ vt_s,
    unsigned char* __restrict__ kd, unsigned char* __restrict__ vd)
{
    const int w    = threadIdx.x >> 6;
    const int lane = threadIdx.x & 63;
    const int l15  = lane & 15;
    const int task = blockIdx.x*4 + w;
    if (task < 4096){
        const int kc = task & 1, n = (task>>1)&7, ch = (task>>4)&7, bh = task>>7;
        const int q4   = lane >> 4;
        const int srow = bh*SN + ch*128 + n*16 + l15;
        const int gb   = srow*16 + kc*8 + q4*2;
        v4i hi, lo;
        dig16(k_q + (size_t)srow*HCN + kc*64 + q4*16, k_s[gb], k_s[gb+1], hi, lo);
        size_t base = (size_t)bh*KD_BH + (size_t)(ch*32768 + n*4096 + kc*2048 + lane*16);
        *(v4i*)(kd + base)        = hi;     // 1KB coalesced wave store (hi plane)
        *(v4i*)(kd + base + 1024) = lo;     // 1KB coalesced wave store (lo plane)
    } else {
        const int t  = task - 4096;
        const int n  = t & 7, kb = (t>>3)&31, bh = t>>8;
        const int sub = lane >> 4;                 // s-quad within fragment
        const int row = bh*HCN + n*16 + l15;       // vt channel row
        const int* vp = vt_q + (size_t)row*SN + kb*32 + sub*8;
        const int s   = vt_s[row*128 + kb*4 + sub];
        unsigned wds[4];
        #pragma unroll
        for (int j=0;j<4;j++){
            int a = vp[j*2]   << s;
            int b = vp[j*2+1] << s;
            wds[j] = (unsigned)bf16_of_int(a) | ((unsigned)bf16_of_int(b) << 16);
        }
        size_t base = (size_t)bh*VD_BH + (size_t)(((kb*8 + n)*64 + lane)*16);
        *(v4i*)(vd + base) = v4i{(int)wds[0],(int)wds[1],(int)wds[2],(int)wds[3]};
    }
}

// ---------------- main fused kernel ----------------
template<bool PK>
__global__ __launch_bounds__(256,2) void mha_mfma(
    const int* __restrict__ q_q, const int* __restrict__ q_s,
    const int* __restrict__ k_q, const int* __restrict__ k_s,
    const int* __restrict__ vt_q, const int* __restrict__ vt_s,
    const unsigned char* __restrict__ kd, const unsigned char* __restrict__ vd,
    int* __restrict__ out)
{
    __shared__ __align__(16) unsigned short rbuf[32*1024];  // 64 KB r values (bf16)
    __shared__ float red[256];                              // cross-wave softmax reductions

    const int tid  = threadIdx.x;
    const int ln   = tid & 15;
    const int qd4  = (tid >> 4) & 3;
    const int w    = tid >> 6;
    const int lane = tid & 63;
    // XCD-aware swizzle: each XCD's share covers only 4 bh -> digit images fit its L2.
    const int blk = blockIdx.x;
    const int bh  = ((blk>>8)<<3) | (blk&7);
    const int t0  = ((blk>>3)&31) * TT;

    // ---- Q fragments in registers for both 16-row halves (B operand, t=ln) ----
    v4i qfh[2][2], qfl[2][2];          // [h][kc]
    #pragma unroll
    for (int h=0; h<2; ++h){
        const int* qrow  = q_q + (size_t)(bh*TN + t0 + h*16 + ln)*HCN;
        const int* qsrow = q_s + (size_t)(bh*TN + t0 + h*16 + ln)*16;
        #pragma unroll
        for (int kc=0; kc<2; ++kc){
            int gi = kc*8 + qd4*2;
            dig16(qrow + kc*64 + qd4*16, qsrow[gi], qsrow[gi+1], qfh[h][kc], qfl[h][kc]);
        }
    }

    int scv[2][16][4];   // C[s][t]: s = (ch*8 + w*2 + i)*16 + qd4*4 + r, t = h*16 + ln

    // ========== phase 1: QK^T scores, transposed (barrier-free, exact int) ==========
    // Every kd load feeds BOTH t-halves (2x reuse vs R8).
    const v4i* kb_ = (const v4i*)(kd + (size_t)bh*KD_BH);
    #pragma unroll
    for (int ch=0; ch<8; ++ch){
        #pragma unroll
        for (int i=0;i<2;i++){
            const int n = w*2 + i;
            v4i a2[2]={{0,0,0,0},{0,0,0,0}}, a1[2]={{0,0,0,0},{0,0,0,0}},
                a0[2]={{0,0,0,0},{0,0,0,0}};
            #pragma unroll
            for (int kc=0;kc<2;kc++){
                v4i bhv, blv;
                if (PK){
                    const v4i* tb = kb_ + (ch*8+n)*256 + kc*128 + lane;
                    bhv = tb[0];
                    blv = tb[64];
                } else {
                    int srow = bh*SN + ch*128 + n*16 + ln;
                    int cc   = kc*64 + qd4*16;
                    dig16(k_q + (size_t)srow*128 + cc,
                          k_s[srow*16 + (cc>>3)], k_s[srow*16 + (cc>>3) + 1], bhv, blv);
                }
                #pragma unroll
                for (int h=0;h<2;h++){
                    a2[h] = __builtin_amdgcn_mfma_i32_16x16x64_i8(bhv, qfh[h][kc], a2[h], 0,0,0);
                    a1[h] = __builtin_amdgcn_mfma_i32_16x16x64_i8(bhv, qfl[h][kc], a1[h], 0,0,0);
                    a1[h] = __builtin_amdgcn_mfma_i32_16x16x64_i8(blv, qfh[h][kc], a1[h], 0,0,0);
                    a0[h] = __builtin_amdgcn_mfma_i32_16x16x64_i8(blv, qfl[h][kc], a0[h], 0,0,0);
                }
            }
            int st = ch*2 + i;
            #pragma unroll
            for (int h=0;h<2;h++)
                #pragma unroll
                for (int r=0;r<4;r++)
                    scv[h][st][r] = (a2[h][r]<<8) + (a1[h][r]<<4) + a0[h][r];
        }
    }

    // ================= softmax over s (log2 domain, hw exp) =================
    // Thread's 64 elements per half belong to ONE output row t = h*16 + ln.
    const float CS2 = (float)(6.103515625e-05 / 11.313708498984760390566
                              * 1.4426950408889634074);
    #pragma unroll
    for (int h=0;h<2;h++){
        float m0=-3.0e38f, m1=-3.0e38f, m2=-3.0e38f, m3=-3.0e38f;
        #pragma unroll
        for (int st=0;st<16;st++){
            float f0 = (float)scv[h][st][0]*CS2; scv[h][st][0]=__float_as_int(f0); m0=fmaxf(m0,f0);
            float f1 = (float)scv[h][st][1]*CS2; scv[h][st][1]=__float_as_int(f1); m1=fmaxf(m1,f1);
            float f2 = (float)scv[h][st][2]*CS2; scv[h][st][2]=__float_as_int(f2); m2=fmaxf(m2,f2);
            float f3 = (float)scv[h][st][3]*CS2; scv[h][st][3]=__float_as_int(f3); m3=fmaxf(m3,f3);
        }
        float m_ = fmaxf(fmaxf(m0,m1), fmaxf(m2,m3));
        m_ = fmaxf(m_, __shfl_xor(m_, 16));
        m_ = fmaxf(m_, __shfl_xor(m_, 32));
        if ((tid & 48) == 0) red[h*64 + w*16 + ln] = m_;
    }
    __syncthreads();
    float inv14[2];
    #pragma unroll
    for (int h=0;h<2;h++){
        const float mrow = fmaxf(fmaxf(red[h*64+ln], red[h*64+16+ln]),
                                 fmaxf(red[h*64+32+ln], red[h*64+48+ln]));
        float s0=0.f, s1=0.f, s2=0.f, s3=0.f;
        #pragma unroll
        for (int st=0;st<16;st++){
            #pragma unroll
            for (int r=0;r<4;r++){
                float t_ = __int_as_float(scv[h][st][r]) - mrow;   // <= 0
                float e;
                asm("v_exp_f32 %0, %1" : "=v"(e) : "v"(t_));       // 2^t
                scv[h][st][r] = __float_as_int(e);
                if (r==0) s0 += e; else if (r==1) s1 += e; else if (r==2) s2 += e; else s3 += e;
            }
        }
        float s_ = (s0+s1) + (s2+s3);
        s_ += __shfl_xor(s_, 16);
        s_ += __shfl_xor(s_, 32);
        if ((tid & 48) == 0) red[128 + h*64 + w*16 + ln] = s_;
    }
    __syncthreads();
    #pragma unroll
    for (int h=0;h<2;h++){
        float sum = red[128+h*64+ln] + red[128+h*64+16+ln]
                  + red[128+h*64+32+ln] + red[128+h*64+48+ln];
        inv14[h] = 16384.0f / sum;     // one IEEE div per row-half
    }

    // ======== group-of-8 po2 requant, in registers -> b64 rbuf stores ========
    // granule = thread's 4 s-values + partner at lane^16; gmax <= 255<<sh so no clamp.
    // swizzle: gs = (g & ~7) | ((g + (ln&7)) & 7); row stride 1024 u16 == 0 mod 128,
    // so bank-group position = gs&7: each 16-lane quarter covers all 8 positions 2x.
    {
        const int lnr = ln & 7;
        const int cbase = w*32 + qd4*4;
        #pragma unroll
        for (int h=0;h<2;h++){
            unsigned short* rp = rbuf + (h*16 + ln)*1024;
            #pragma unroll
            for (int st=0;st<16;st++){
                float v0 = rintf(__int_as_float(scv[h][st][0]) * inv14[h]);
                float v1 = rintf(__int_as_float(scv[h][st][1]) * inv14[h]);
                float v2 = rintf(__int_as_float(scv[h][st][2]) * inv14[h]);
                float v3 = rintf(__int_as_float(scv[h][st][3]) * inv14[h]);
                float g = fmaxf(fmaxf(v0,v1), fmaxf(v2,v3));
                g = fmaxf(g, __shfl_xor(g, 16));            // partner half of the granule
                int gi = max((int)g, 1);
                int x  = gi - 1;
                int e2 = 31 - __clz(x | 255);
                int sh = (e2 - 7) + ((x >> (e2 - 7)) == 255); // clip(ceil(log2(gi/255)),0,)
                float isc = __int_as_float((127 - sh) << 23); // exact 2^-sh
                float fsc = __int_as_float((127 + sh) << 23); // exact 2^sh
                unsigned b0 = __float_as_uint(rintf(v0*isc) * fsc);  // r = rq<<sh, 8 sig bits
                unsigned b1 = __float_as_uint(rintf(v1*isc) * fsc);
                unsigned b2 = __float_as_uint(rintf(v2*isc) * fsc);
                unsigned b3 = __float_as_uint(rintf(v3*isc) * fsc);
                unsigned w0 = __builtin_amdgcn_perm(b1, b0, 0x07060302u); // {bf16(v0),bf16(v1)}
                unsigned w1 = __builtin_amdgcn_perm(b3, b2, 0x07060302u);
                int c0 = (st>>1)*128 + cbase + (st&1)*16;  // col of v0 (c0&7 in {0,4})
                int g_ = c0 >> 3;
                int gs = (g_ & 0x78) | ((g_ + lnr) & 7);
                *(v2u*)(rp + gs*8 + (c0&7)) = v2u{w0, w1};   // one b64 store per tile
            }
        }
    }
    __syncthreads();

    // ========= phase 2: out = r @ vt^T (bf16 MFMA, both halves share vd loads) =========
    const v4i* vb = (const v4i*)(vd + (size_t)bh*VD_BH);
    const unsigned short* rp0 = rbuf + ln*1024;
    const unsigned short* rp1 = rbuf + (16 + ln)*1024;
    const int lnr2 = ln & 7;
    v4f acc00{0,0,0,0}, acc01{0,0,0,0}, acc10{0,0,0,0}, acc11{0,0,0,0};
    #pragma unroll 4
    for (int kb=0; kb<32; ++kb){
        // A frags: r[t][s = kb*32 + qd4*8 + j], 8 bf16 = one b128 from LDS per half
        int g2  = kb*4 + qd4;
        int gs2 = (g2 & 0x78) | ((g2 + lnr2) & 7);
        v8s af0 = *(const v8s*)(rp0 + gs2*8);
        v8s af1 = *(const v8s*)(rp1 + gs2*8);
        v4i b0, b1;
        if (PK){
            b0 = vb[(kb*8 + w*2    )*64 + lane];
            b1 = vb[(kb*8 + w*2 + 1)*64 + lane];
        } else {
            #pragma unroll
            for (int i=0;i<2;i++){
                int chan = (w*2+i)*16 + ln;
                const int* vp = vt_q + (size_t)(bh*HCN + chan)*SN + kb*32 + qd4*8;
                int s = vt_s[(bh*HCN + chan)*128 + kb*4 + qd4];
                unsigned wd[4];
                #pragma unroll
                for (int j=0;j<4;j++){
                    int a = vp[j*2]   << s;
                    int b = vp[j*2+1] << s;
                    wd[j] = (unsigned)bf16_of_int(a) | ((unsigned)bf16_of_int(b)<<16);
                }
                v4i t{(int)wd[0],(int)wd[1],(int)wd[2],(int)wd[3]};
                if (i==0) b0 = t; else b1 = t;
            }
        }
        v8s bs0, bs1;
        memcpy(&bs0, &b0, 16);
        memcpy(&bs1, &b1, 16);
        acc00 = __builtin_amdgcn_mfma_f32_16x16x32_bf16(af0, bs0, acc00, 0,0,0);
        acc01 = __builtin_amdgcn_mfma_f32_16x16x32_bf16(af0, bs1, acc01, 0,0,0);
        acc10 = __builtin_amdgcn_mfma_f32_16x16x32_bf16(af1, bs0, acc10, 0,0,0);
        acc11 = __builtin_amdgcn_mfma_f32_16x16x32_bf16(af1, bs1, acc11, 0,0,0);
    }
    #pragma unroll
    for (int r=0;r<4;r++){
        size_t o0 = (size_t)(bh*TN + t0 + qd4*4 + r)*HCN + w*32 + ln;
        out[o0]      = (int)rintf(acc00[r]);
        out[o0 + 16] = (int)rintf(acc01[r]);
        size_t o1 = o0 + (size_t)16*HCN;
        out[o1]      = (int)rintf(acc10[r]);
        out[o1 + 16] = (int)rintf(acc11[r]);
    }
}

extern "C" void kernel_launch(void* const* d_in, const int* in_sizes, int n_in,
                              void* d_out, int out_size, void* d_ws, size_t ws_size,
                              hipStream_t stream) {
    const int* q_q  = (const int*)d_in[0];
    const int* q_s  = (const int*)d_in[1];
    const int* k_q  = (const int*)d_in[2];
    const int* k_s  = (const int*)d_in[3];
    const int* vt_q = (const int*)d_in[4];
    const int* vt_s = (const int*)d_in[5];
    int* out = (int*)d_out;

    unsigned char* kd = (unsigned char*)d_ws;
    unsigned char* vd = kd + (size_t)BHN*KD_BH;

    if (ws_size >= WS_NEED){
        // 12288 wave-tasks (4096 kd + 8192 vd), 4 waves/block
        digitize<<<dim3(3072), 256, 0, stream>>>(k_q,k_s,vt_q,vt_s, kd,vd);
        mha_mfma<true><<<dim3(1024), 256, 0, stream>>>(
            q_q,q_s,k_q,k_s,vt_q,vt_s, kd,vd, out);
    } else {
        mha_mfma<false><<<dim3(1024), 256, 0, stream>>>(
            q_q,q_s,k_q,k_s,vt_q,vt_s, kd,vd, out);
    }
}

// Round 4
// 152.034 us; speedup vs baseline: 1.1626x; 1.1626x over previous
//
#include <hip/hip_runtime.h>
#include <string.h>

// Integer-quantized MHA. Phase 1: exact-int i8 K=64 MFMA digit GEMM, TRANSPOSED
// (C[s][t] via mfma(K,Q)) so the S-axis quant group is lane-local. Phase 2:
// native bf16 MFMA (r_q<=255, vt mantissa 8-bit -> exact products).
// R10 = R8 structure (61us, known-good TT=16) + fixes:
//  - R9's TT=32 REVERTED: scv[2][16][4] spilled to scratch (WRITE_SIZE 16->72MB,
//    FETCH 17->45MB, occupancy 20%) -> 87us. Register cost, not L2, was binding.
//  - corrected LDS swizzle KEPT (validated in R9: conflicts 5.77M->1.57M even
//    while spilled): RST=1024 (no pad), gs = (g&~7)|((g+(ln&7))&7) on both store
//    and read; remaining alias is the free 2-way ln/ln+8 kind.
//  - softmax max pass in INT domain (monotone scale): pure int max tree
//    (v_max3_i32), no float rewrite of scv; exp pass does (s-m) exact in i32
//    then one cvt+mul+v_exp_f32. ~60 VALU/thread saved vs R8.
// B=2,H=16 (BH=32), T=S=1024, HC=128, G=8. Output int32.

typedef int   v4i __attribute__((ext_vector_type(4)));
typedef float v4f __attribute__((ext_vector_type(4)));
typedef short v8s __attribute__((ext_vector_type(8)));
typedef unsigned v2u __attribute__((ext_vector_type(2)));

#define BHN 32
#define TN  1024
#define SN  1024
#define HCN 128
#define TT  16
#define KD_BH 262144           // 8 chunks * 32 KB (2 planes, fragment-ordered)
#define VD_BH 262144           // 32 kb * 8 n * 64 lanes * 16 B (bf16 frags)
#define WS_NEED ((size_t)BHN*(KD_BH+VD_BH))   // 16 MB

__device__ __forceinline__ unsigned pack_b(int b0,int b1,int b2,int b3){
    return (unsigned)((b0&255)|((b1&255)<<8)|((b2&255)<<16)|((b3&255)<<24));
}

// digitize 16 consecutive dequantized ints (2 scale groups) into hi/lo i8 digit vectors
__device__ __forceinline__ void dig16(const int* __restrict__ p, int s0, int s1,
                                      v4i& hi, v4i& lo){
    #pragma unroll
    for (int wi=0; wi<4; ++wi){
        v4i m = *(const v4i*)(p + wi*4);
        int s = (wi<2) ? s0 : s1;
        int d0=m[0]<<s, d1=m[1]<<s, d2=m[2]<<s, d3=m[3]<<s;
        hi[wi] = (int)pack_b(d0>>4,d1>>4,d2>>4,d3>>4);
        lo[wi] = (int)pack_b(d0&15,d1&15,d2&15,d3&15);
    }
}

__device__ __forceinline__ unsigned short bf16_of_int(int v){
    return (unsigned short)(__float_as_uint((float)v) >> 16);   // exact: <=8 sig bits
}

// ---------------- pre-pass (gather form: coalesced stores) ----------------
// kd: per bh, [ch(8)][n(8)][kc(2)][plane(2:hi,lo)][lane64][16B]
// vd: per bh, [kb(32)][n(8)][lane64][16B]  (8 bf16 per lane)
// One wave per fragment tile: wave stores lane*16 -> contiguous 1KB per store.
// Tasks: 0..4095 = kd (bh*128+ch*16+n*2+kc); 4096..12287 = vd (bh*256+kb*8+n).
__global__ __launch_bounds__(256) void digitize(
    const int* __restrict__ k_q, const int* __restrict__ k_s,
    const int* __restrict__ vt_q, const int* __restrict__ vt_s,
    unsigned char* __restrict__ kd, unsigned char* __restrict__ vd)
{
    const int w    = threadIdx.x >> 6;
    const int lane = threadIdx.x & 63;
    const int l15  = lane & 15;
    const int task = blockIdx.x*4 + w;
    if (task < 4096){
        const int kc = task & 1, n = (task>>1)&7, ch = (task>>4)&7, bh = task>>7;
        const int q4   = lane >> 4;
        const int srow = bh*SN + ch*128 + n*16 + l15;
        const int gb   = srow*16 + kc*8 + q4*2;
        v4i hi, lo;
        dig16(k_q + (size_t)srow*HCN + kc*64 + q4*16, k_s[gb], k_s[gb+1], hi, lo);
        size_t base = (size_t)bh*KD_BH + (size_t)(ch*32768 + n*4096 + kc*2048 + lane*16);
        *(v4i*)(kd + base)        = hi;     // 1KB coalesced wave store (hi plane)
        *(v4i*)(kd + base + 1024) = lo;     // 1KB coalesced wave store (lo plane)
    } else {
        const int t  = task - 4096;
        const int n  = t & 7, kb = (t>>3)&31, bh = t>>8;
        const int sub = lane >> 4;                 // s-quad within fragment
        const int row = bh*HCN + n*16 + l15;       // vt channel row
        const int* vp = vt_q + (size_t)row*SN + kb*32 + sub*8;
        const int s   = vt_s[row*128 + kb*4 + sub];
        unsigned wds[4];
        #pragma unroll
        for (int j=0;j<4;j++){
            int a = vp[j*2]   << s;
            int b = vp[j*2+1] << s;
            wds[j] = (unsigned)bf16_of_int(a) | ((unsigned)bf16_of_int(b) << 16);
        }
        size_t base = (size_t)bh*VD_BH + (size_t)(((kb*8 + n)*64 + lane)*16);
        *(v4i*)(vd + base) = v4i{(int)wds[0],(int)wds[1],(int)wds[2],(int)wds[3]};
    }
}

// ---------------- main fused kernel ----------------
template<bool PK>
__global__ __launch_bounds__(256,4) void mha_mfma(
    const int* __restrict__ q_q, const int* __restrict__ q_s,
    const int* __restrict__ k_q, const int* __restrict__ k_s,
    const int* __restrict__ vt_q, const int* __restrict__ vt_s,
    const unsigned char* __restrict__ kd, const unsigned char* __restrict__ vd,
    int* __restrict__ out)
{
    __shared__ __align__(16) unsigned short rbuf[16*1024];  // 32 KB r values (bf16)
    __shared__ float red[64];                               // cross-wave sum reduction
    __shared__ int   redi[64];                              // cross-wave int max reduction

    const int tid  = threadIdx.x;
    const int ln   = tid & 15;
    const int qd4  = (tid >> 4) & 3;
    const int w    = tid >> 6;
    const int lane = tid & 63;
    // XCD-aware swizzle: each XCD's share covers only 4 bh -> digit images fit its L2.
    const int blk = blockIdx.x;
    const int bh  = ((blk>>9)<<3) | (blk&7);
    const int t0  = ((blk>>3)&63) * TT;

    // ---- Q fragments in registers (B operand in phase 1, t=ln) ----
    v4i qfh[2], qfl[2];
    {
        const int* qrow  = q_q + (size_t)(bh*TN + t0 + ln)*HCN;
        const int* qsrow = q_s + (size_t)(bh*TN + t0 + ln)*16;
        #pragma unroll
        for (int kc=0; kc<2; ++kc){
            int gi = kc*8 + qd4*2;
            dig16(qrow + kc*64 + qd4*16, qsrow[gi], qsrow[gi+1], qfh[kc], qfl[kc]);
        }
    }

    int scv[16][4];   // C[s][t]: s = (ch*8 + w*2 + i)*16 + qd4*4 + r, t = ln

    // ========== phase 1: QK^T scores, transposed (barrier-free, exact int) ==========
    const v4i* kb_ = (const v4i*)(kd + (size_t)bh*KD_BH);
    #pragma unroll
    for (int ch=0; ch<8; ++ch){
        #pragma unroll
        for (int i=0;i<2;i++){
            const int n = w*2 + i;
            v4i a2{0,0,0,0}, a1{0,0,0,0}, a0{0,0,0,0};
            #pragma unroll
            for (int kc=0;kc<2;kc++){
                v4i bhv, blv;
                if (PK){
                    const v4i* tb = kb_ + (ch*8+n)*256 + kc*128 + lane;
                    bhv = tb[0];
                    blv = tb[64];
                } else {
                    int srow = bh*SN + ch*128 + n*16 + ln;
                    int cc   = kc*64 + qd4*16;
                    dig16(k_q + (size_t)srow*128 + cc,
                          k_s[srow*16 + (cc>>3)], k_s[srow*16 + (cc>>3) + 1], bhv, blv);
                }
                // A = K digits, B = Q digits  ->  C[s][t]
                a2 = __builtin_amdgcn_mfma_i32_16x16x64_i8(bhv, qfh[kc], a2, 0,0,0);
                a1 = __builtin_amdgcn_mfma_i32_16x16x64_i8(bhv, qfl[kc], a1, 0,0,0);
                a1 = __builtin_amdgcn_mfma_i32_16x16x64_i8(blv, qfh[kc], a1, 0,0,0);
                a0 = __builtin_amdgcn_mfma_i32_16x16x64_i8(blv, qfl[kc], a0, 0,0,0);
            }
            int st = ch*2 + i;
            #pragma unroll
            for (int r=0;r<4;r++)
                scv[st][r] = (a2[r]<<8) + (a1[r]<<4) + a0[r];
        }
    }

    // ================= softmax over s (int-domain max, log2-domain exp) =================
    // Thread's 64 elements belong to ONE output row t=ln. Scale is positive ->
    // argmax over raw int scores == argmax over logits (monotone).
    const float CS2 = (float)(6.103515625e-05 / 11.313708498984760390566
                              * 1.4426950408889634074);
    {
        int m0=-2147483647, m1=-2147483647, m2=-2147483647, m3=-2147483647;
        #pragma unroll
        for (int st=0;st<16;st++){
            m0 = max(m0, scv[st][0]);
            m1 = max(m1, scv[st][1]);
            m2 = max(m2, scv[st][2]);
            m3 = max(m3, scv[st][3]);
        }
        int m_ = max(max(m0,m1), max(m2,m3));
        m_ = max(m_, __shfl_xor(m_, 16));
        m_ = max(m_, __shfl_xor(m_, 32));
        if ((tid & 48) == 0) redi[w*16 + ln] = m_;
    }
    __syncthreads();
    float inv14;
    {
        const int mrow = max(max(redi[ln], redi[16+ln]), max(redi[32+ln], redi[48+ln]));
        float s0=0.f, s1=0.f, s2=0.f, s3=0.f;
        #pragma unroll
        for (int st=0;st<16;st++){
            #pragma unroll
            for (int r=0;r<4;r++){
                float t_ = (float)(scv[st][r] - mrow) * CS2;   // <= 0, diff exact in i32
                float e;
                asm("v_exp_f32 %0, %1" : "=v"(e) : "v"(t_));   // 2^t
                scv[st][r] = __float_as_int(e);
                if (r==0) s0 += e; else if (r==1) s1 += e; else if (r==2) s2 += e; else s3 += e;
            }
        }
        float s_ = (s0+s1) + (s2+s3);
        s_ += __shfl_xor(s_, 16);
        s_ += __shfl_xor(s_, 32);
        if ((tid & 48) == 0) red[w*16 + ln] = s_;
    }
    __syncthreads();
    {
        float sum = red[ln] + red[16+ln] + red[32+ln] + red[48+ln];
        inv14 = 16384.0f / sum;        // one IEEE div per thread
    }

    // ======== group-of-8 po2 requant, in registers -> b64 rbuf stores ========
    // granule = thread's 4 s-values + partner at lane^16; gmax <= 255<<sh so no clamp.
    // swizzle (R9-validated): row stride 1024 u16 (0 mod 128), granule slot
    // gs = (g&~7)|((g+(ln&7))&7): per 16-lane quarter every bank-group position
    // is hit exactly 2x (ln / ln+8, different rows) = free 2-way.
    {
        const int lnr = ln & 7;
        const int cbase = w*32 + qd4*4;
        unsigned short* rp = rbuf + ln*1024;
        #pragma unroll
        for (int st=0;st<16;st++){
            float v0 = rintf(__int_as_float(scv[st][0]) * inv14);
            float v1 = rintf(__int_as_float(scv[st][1]) * inv14);
            float v2 = rintf(__int_as_float(scv[st][2]) * inv14);
            float v3 = rintf(__int_as_float(scv[st][3]) * inv14);
            float g = fmaxf(fmaxf(v0,v1), fmaxf(v2,v3));
            g = fmaxf(g, __shfl_xor(g, 16));            // partner half of the granule
            int gi = max((int)g, 1);
            int x  = gi - 1;
            int e2 = 31 - __clz(x | 255);
            int sh = (e2 - 7) + ((x >> (e2 - 7)) == 255); // clip(ceil(log2(gi/255)),0,)
            float isc = __int_as_float((127 - sh) << 23); // exact 2^-sh
            float fsc = __int_as_float((127 + sh) << 23); // exact 2^sh
            unsigned b0 = __float_as_uint(rintf(v0*isc) * fsc);  // r = rq<<sh, 8 sig bits
            unsigned b1 = __float_as_uint(rintf(v1*isc) * fsc);
            unsigned b2 = __float_as_uint(rintf(v2*isc) * fsc);
            unsigned b3 = __float_as_uint(rintf(v3*isc) * fsc);
            unsigned w0 = __builtin_amdgcn_perm(b1, b0, 0x07060302u); // {bf16(v0),bf16(v1)}
            unsigned w1 = __builtin_amdgcn_perm(b3, b2, 0x07060302u);
            int c0 = (st>>1)*128 + cbase + (st&1)*16;  // col of v0 (c0&7 in {0,4})
            int g_ = c0 >> 3;
            int gs = (g_ & 0x78) | ((g_ + lnr) & 7);
            *(v2u*)(rp + gs*8 + (c0&7)) = v2u{w0, w1};   // one b64 store per tile
        }
    }
    __syncthreads();

    // ================= phase 2: out = r @ vt^T (bf16 MFMA, barrier-free) =================
    const v4i* vb = (const v4i*)(vd + (size_t)bh*VD_BH);
    const unsigned short* rp2 = rbuf + ln*1024;
    const int lnr2 = ln & 7;
    v4f acc0{0,0,0,0}, acc1{0,0,0,0};
    #pragma unroll 4
    for (int kb=0; kb<32; ++kb){
        // A frag: r[t=ln][s = kb*32 + qd4*8 + j], 8 bf16 = one b128 from LDS
        int g2  = kb*4 + qd4;
        int gs2 = (g2 & 0x78) | ((g2 + lnr2) & 7);
        v8s af = *(const v8s*)(rp2 + gs2*8);
        v4i b0, b1;
        if (PK){
            b0 = vb[(kb*8 + w*2    )*64 + lane];
            b1 = vb[(kb*8 + w*2 + 1)*64 + lane];
        } else {
            #pragma unroll
            for (int i=0;i<2;i++){
                int chan = (w*2+i)*16 + ln;
                const int* vp = vt_q + (size_t)(bh*HCN + chan)*SN + kb*32 + qd4*8;
                int s = vt_s[(bh*HCN + chan)*128 + kb*4 + qd4];
                unsigned wd[4];
                #pragma unroll
                for (int j=0;j<4;j++){
                    int a = vp[j*2]   << s;
                    int b = vp[j*2+1] << s;
                    wd[j] = (unsigned)bf16_of_int(a) | ((unsigned)bf16_of_int(b)<<16);
                }
                v4i t{(int)wd[0],(int)wd[1],(int)wd[2],(int)wd[3]};
                if (i==0) b0 = t; else b1 = t;
            }
        }
        v8s bs0, bs1;
        memcpy(&bs0, &b0, 16);
        memcpy(&bs1, &b1, 16);
        acc0 = __builtin_amdgcn_mfma_f32_16x16x32_bf16(af, bs0, acc0, 0,0,0);
        acc1 = __builtin_amdgcn_mfma_f32_16x16x32_bf16(af, bs1, acc1, 0,0,0);
    }
    #pragma unroll
    for (int r=0;r<4;r++){
        size_t o = (size_t)(bh*TN + t0 + qd4*4 + r)*HCN + w*32 + ln;
        out[o]      = (int)rintf(acc0[r]);
        out[o + 16] = (int)rintf(acc1[r]);
    }
}

extern "C" void kernel_launch(void* const* d_in, const int* in_sizes, int n_in,
                              void* d_out, int out_size, void* d_ws, size_t ws_size,
                              hipStream_t stream) {
    const int* q_q  = (const int*)d_in[0];
    const int* q_s  = (const int*)d_in[1];
    const int* k_q  = (const int*)d_in[2];
    const int* k_s  = (const int*)d_in[3];
    const int* vt_q = (const int*)d_in[4];
    const int* vt_s = (const int*)d_in[5];
    int* out = (int*)d_out;

    unsigned char* kd = (unsigned char*)d_ws;
    unsigned char* vd = kd + (size_t)BHN*KD_BH;

    if (ws_size >= WS_NEED){
        // 12288 wave-tasks (4096 kd + 8192 vd), 4 waves/block
        digitize<<<dim3(3072), 256, 0, stream>>>(k_q,k_s,vt_q,vt_s, kd,vd);
        mha_mfma<true><<<dim3(2048), 256, 0, stream>>>(
            q_q,q_s,k_q,k_s,vt_q,vt_s, kd,vd, out);
    } else {
        mha_mfma<false><<<dim3(2048), 256, 0, stream>>>(
            q_q,q_s,k_q,k_s,vt_q,vt_s, kd,vd, out);
    }
}